// Round 1
// baseline (5442.664 us; speedup 1.0000x reference)
//
#include <hip/hip_runtime.h>
#include <hip/hip_bf16.h>

#define N_NODES 20000
#define N_EDGES 160000
#define DIN_NODE 256
#define DIN_EDGE 64
#define DF 128      // feature dim
#define HH 256      // edge-MLP hidden dim
#define TT 17       // node types

// ---------------------------------------------------------------------------
// Node embedding: type-routed 2-layer MLP 256 -> 128 (relu) -> 128.
// Block = 256 threads handles 2 nodes (group g = tid>>7 picks the node).
// ---------------------------------------------------------------------------
__global__ __launch_bounds__(256) void k_node_embed(
    const float* __restrict__ x, const int* __restrict__ types,
    const float* __restrict__ w1, const float* __restrict__ b1,
    const float* __restrict__ w2, const float* __restrict__ b2,
    float* __restrict__ nf0) {
  __shared__ float x_lds[2][DIN_NODE];
  __shared__ float h_lds[2][DF];
  const int t = threadIdx.x;
  const int g = t >> 7, h = t & 127;
  const int n0 = blockIdx.x * 2;
  // stage the two input rows (256 threads x 2 rows)
  x_lds[0][t] = x[(size_t)n0 * DIN_NODE + t];
  x_lds[1][t] = x[(size_t)(n0 + 1) * DIN_NODE + t];
  __syncthreads();
  const int n = n0 + g;
  const int ty = types[n];
  const float* W1 = w1 + (size_t)ty * DIN_NODE * DF;
  float acc = b1[ty * DF + h];
  for (int k = 0; k < DIN_NODE; ++k)
    acc = fmaf(x_lds[g][k], W1[k * DF + h], acc);
  h_lds[g][h] = fmaxf(acc, 0.f);
  __syncthreads();
  const float* W2 = w2 + (size_t)ty * DF * DF;
  float acc2 = b2[ty * DF + h];
  for (int k = 0; k < DF; ++k)
    acc2 = fmaf(h_lds[g][k], W2[k * DF + h], acc2);
  nf0[(size_t)n * DF + h] = acc2;
}

// ---------------------------------------------------------------------------
// Edge embedding: 64 -> 128 (relu) -> 128.  Block = 256 threads, 32 edges.
// ---------------------------------------------------------------------------
#define EB_TILE 32
__global__ __launch_bounds__(256) void k_edge_embed(
    const float* __restrict__ ea,
    const float* __restrict__ w1, const float* __restrict__ b1,
    const float* __restrict__ w2, const float* __restrict__ b2,
    float* __restrict__ ef0) {
  __shared__ float a_lds[EB_TILE][DIN_EDGE];   // 8 KB
  __shared__ float h_lds[EB_TILE][DF];         // 16 KB
  const int t = threadIdx.x;
  const int e0 = blockIdx.x * EB_TILE;
  // stage 32x64 inputs: 2048 elems, 8 per thread
#pragma unroll
  for (int j = 0; j < 8; ++j) {
    int idx = j * 256 + t;
    int i = idx >> 6, c = idx & 63;
    a_lds[i][c] = ea[(size_t)(e0 + i) * DIN_EDGE + c];
  }
  __syncthreads();
  const int g = t >> 7, h = t & 127;
  float acc[16];
#pragma unroll
  for (int i = 0; i < 16; ++i) acc[i] = 0.f;
  for (int k4 = 0; k4 < DIN_EDGE / 4; ++k4) {
    const float wa = w1[(k4 * 4 + 0) * DF + h];
    const float wb = w1[(k4 * 4 + 1) * DF + h];
    const float wc = w1[(k4 * 4 + 2) * DF + h];
    const float wd = w1[(k4 * 4 + 3) * DF + h];
#pragma unroll
    for (int i = 0; i < 16; ++i) {
      const float4 m = *reinterpret_cast<const float4*>(&a_lds[2 * i + g][k4 * 4]);
      acc[i] = fmaf(m.x, wa, fmaf(m.y, wb, fmaf(m.z, wc, fmaf(m.w, wd, acc[i]))));
    }
  }
  const float bb = b1[h];
#pragma unroll
  for (int i = 0; i < 16; ++i) h_lds[2 * i + g][h] = fmaxf(acc[i] + bb, 0.f);
  __syncthreads();
  float acc2[16];
#pragma unroll
  for (int i = 0; i < 16; ++i) acc2[i] = 0.f;
  for (int k4 = 0; k4 < DF / 4; ++k4) {
    const float wa = w2[(k4 * 4 + 0) * DF + h];
    const float wb = w2[(k4 * 4 + 1) * DF + h];
    const float wc = w2[(k4 * 4 + 2) * DF + h];
    const float wd = w2[(k4 * 4 + 3) * DF + h];
#pragma unroll
    for (int i = 0; i < 16; ++i) {
      const float4 m = *reinterpret_cast<const float4*>(&h_lds[2 * i + g][k4 * 4]);
      acc2[i] = fmaf(m.x, wa, fmaf(m.y, wb, fmaf(m.z, wc, fmaf(m.w, wd, acc2[i]))));
    }
  }
  const float b2v = b2[h];
#pragma unroll
  for (int i = 0; i < 16; ++i)
    ef0[(size_t)(e0 + 2 * i + g) * DF + h] = acc2[i] + b2v;
}

// ---------------------------------------------------------------------------
// Edge MLP (the big one): m[768] = [nf_c[dst] | nf_c[src] | ef_c],
// hidden = relu(m @ w1 + b1) [256], e_new = hidden @ w2 + b2 [128].
// Also atomically accumulates e_new into agg[dst].
// Block = 256 threads, 16 edges.  In-place-safe on ef (own rows only).
// ---------------------------------------------------------------------------
#define EM_TILE 16
__global__ __launch_bounds__(256) void k_edge_mlp(
    const float* __restrict__ nf0, const float* __restrict__ nf,
    const float* __restrict__ ef0, const float* __restrict__ ef_in,
    float* __restrict__ ef_out, float* __restrict__ agg,
    const int* __restrict__ srcv, const int* __restrict__ dstv,
    const float* __restrict__ w1, const float* __restrict__ b1,
    const float* __restrict__ w2, const float* __restrict__ b2) {
  __shared__ float m_lds[EM_TILE][6 * DF];   // 16 x 768 = 48 KB
  __shared__ int sd[2][EM_TILE];
  const int t = threadIdx.x;
  const int e0 = blockIdx.x * EM_TILE;
  if (t < EM_TILE) sd[0][t] = srcv[e0 + t];
  else if (t < 2 * EM_TILE) sd[1][t - EM_TILE] = dstv[e0 + t - EM_TILE];
  __syncthreads();
  const int g = t >> 7, lane = t & 127;
  // gather: 96 segments of 128 floats (16 edges x 6 parts), wave-uniform p
  for (int j = 0; j < 48; ++j) {
    const int s = 2 * j + g;
    const int i = s / 6, p = s % 6;
    const int e = e0 + i;
    const float* base;
    switch (p) {
      case 0: base = nf0 + (size_t)sd[1][i] * DF; break;   // nf0[dst]
      case 1: base = nf + (size_t)sd[1][i] * DF; break;    // nf[dst]
      case 2: base = nf0 + (size_t)sd[0][i] * DF; break;   // nf0[src]
      case 3: base = nf + (size_t)sd[0][i] * DF; break;    // nf[src]
      case 4: base = ef0 + (size_t)e * DF; break;          // ef0[e]
      default: base = ef_in + (size_t)e * DF; break;       // ef[e]
    }
    m_lds[i][p * DF + lane] = base[lane];
  }
  __syncthreads();
  // layer 1: each thread owns hidden column t (256 cols), 16 edges
  float acc[EM_TILE];
#pragma unroll
  for (int i = 0; i < EM_TILE; ++i) acc[i] = 0.f;
  for (int k4 = 0; k4 < (6 * DF) / 4; ++k4) {   // 192
    const float wa = w1[(k4 * 4 + 0) * HH + t];
    const float wb = w1[(k4 * 4 + 1) * HH + t];
    const float wc = w1[(k4 * 4 + 2) * HH + t];
    const float wd = w1[(k4 * 4 + 3) * HH + t];
#pragma unroll
    for (int i = 0; i < EM_TILE; ++i) {
      const float4 m = *reinterpret_cast<const float4*>(&m_lds[i][k4 * 4]);
      acc[i] = fmaf(m.x, wa, fmaf(m.y, wb, fmaf(m.z, wc, fmaf(m.w, wd, acc[i]))));
    }
  }
  const float bb = b1[t];
  __syncthreads();               // everyone done reading m_lds
  float* hv = &m_lds[0][0];      // reuse as hidden [16][256]
#pragma unroll
  for (int i = 0; i < EM_TILE; ++i) hv[i * HH + t] = fmaxf(acc[i] + bb, 0.f);
  __syncthreads();
  // layer 2: outputs 16 edges x 128 dims; thread owns d=lane, 8 edges
  float acc2[8];
#pragma unroll
  for (int i = 0; i < 8; ++i) acc2[i] = 0.f;
  for (int k4 = 0; k4 < HH / 4; ++k4) {   // 64
    const float wa = w2[(k4 * 4 + 0) * DF + lane];
    const float wb = w2[(k4 * 4 + 1) * DF + lane];
    const float wc = w2[(k4 * 4 + 2) * DF + lane];
    const float wd = w2[(k4 * 4 + 3) * DF + lane];
#pragma unroll
    for (int i = 0; i < 8; ++i) {
      const float4 m = *reinterpret_cast<const float4*>(&hv[(2 * i + g) * HH + k4 * 4]);
      acc2[i] = fmaf(m.x, wa, fmaf(m.y, wb, fmaf(m.z, wc, fmaf(m.w, wd, acc2[i]))));
    }
  }
  const float b2v = b2[lane];
#pragma unroll
  for (int i = 0; i < 8; ++i) {
    const int ei = 2 * i + g;
    const float v = acc2[i] + b2v;
    ef_out[(size_t)(e0 + ei) * DF + lane] = v;
    atomicAdd(&agg[(size_t)sd[1][ei] * DF + lane], v);
  }
}

// ---------------------------------------------------------------------------
// Node update: nf_new = [nf0 | nf | agg] (384) @ w (384x128) + b.  No relu.
// Block = 256 threads, 16 nodes.  In-place-safe (own rows staged first).
// ---------------------------------------------------------------------------
#define NU_TILE 16
__global__ __launch_bounds__(256) void k_node_update(
    const float* __restrict__ nf0, const float* __restrict__ nf_in,
    const float* __restrict__ agg, float* __restrict__ nf_out,
    const float* __restrict__ w, const float* __restrict__ b) {
  __shared__ float c_lds[NU_TILE][3 * DF];   // 16 x 384 = 24 KB
  const int t = threadIdx.x;
  const int n0 = blockIdx.x * NU_TILE;
  const int g = t >> 7, lane = t & 127;
  for (int j = 0; j < 24; ++j) {
    const int s = 2 * j + g;   // 48 segments
    const int i = s / 3, p = s % 3;
    const float* base = (p == 0) ? nf0 + (size_t)(n0 + i) * DF
                      : (p == 1) ? nf_in + (size_t)(n0 + i) * DF
                                 : agg + (size_t)(n0 + i) * DF;
    c_lds[i][p * DF + lane] = base[lane];
  }
  __syncthreads();
  float acc[8];
#pragma unroll
  for (int i = 0; i < 8; ++i) acc[i] = 0.f;
  for (int k4 = 0; k4 < (3 * DF) / 4; ++k4) {   // 96
    const float wa = w[(k4 * 4 + 0) * DF + lane];
    const float wb = w[(k4 * 4 + 1) * DF + lane];
    const float wc = w[(k4 * 4 + 2) * DF + lane];
    const float wd = w[(k4 * 4 + 3) * DF + lane];
#pragma unroll
    for (int i = 0; i < 8; ++i) {
      const float4 m = *reinterpret_cast<const float4*>(&c_lds[2 * i + g][k4 * 4]);
      acc[i] = fmaf(m.x, wa, fmaf(m.y, wb, fmaf(m.z, wc, fmaf(m.w, wd, acc[i]))));
    }
  }
  const float bv = b[lane];
#pragma unroll
  for (int i = 0; i < 8; ++i)
    nf_out[(size_t)(n0 + 2 * i + g) * DF + lane] = acc[i] + bv;
}

// ---------------------------------------------------------------------------
// Scalar classifier head: relu(f @ w1 + b1) @ w2[128] + b2 -> out[r] (1 value)
// Block = 256 threads, 32 rows.
// ---------------------------------------------------------------------------
#define SC_TILE 32
__global__ __launch_bounds__(256) void k_cls_scalar(
    const float* __restrict__ feat,
    const float* __restrict__ w1, const float* __restrict__ b1,
    const float* __restrict__ w2, const float* __restrict__ b2,
    float* __restrict__ out) {
  __shared__ float f_lds[SC_TILE][DF];        // 16 KB
  __shared__ float h_lds[SC_TILE][DF + 1];    // padded (phase-2 column reads)
  __shared__ float w2_lds[DF];
  const int t = threadIdx.x;
  const int r0 = blockIdx.x * SC_TILE;
  if (t < DF) w2_lds[t] = w2[t];
#pragma unroll
  for (int j = 0; j < 16; ++j) {
    int idx = j * 256 + t;
    int i = idx >> 7, c = idx & 127;
    f_lds[i][c] = feat[(size_t)(r0 + i) * DF + c];
  }
  __syncthreads();
  const int g = t >> 7, h = t & 127;
  float acc[16];
#pragma unroll
  for (int i = 0; i < 16; ++i) acc[i] = 0.f;
  for (int k4 = 0; k4 < DF / 4; ++k4) {
    const float wa = w1[(k4 * 4 + 0) * DF + h];
    const float wb = w1[(k4 * 4 + 1) * DF + h];
    const float wc = w1[(k4 * 4 + 2) * DF + h];
    const float wd = w1[(k4 * 4 + 3) * DF + h];
#pragma unroll
    for (int i = 0; i < 16; ++i) {
      const float4 m = *reinterpret_cast<const float4*>(&f_lds[2 * i + g][k4 * 4]);
      acc[i] = fmaf(m.x, wa, fmaf(m.y, wb, fmaf(m.z, wc, fmaf(m.w, wd, acc[i]))));
    }
  }
  const float bb = b1[h];
#pragma unroll
  for (int i = 0; i < 16; ++i) h_lds[2 * i + g][h] = fmaxf(acc[i] + bb, 0.f);
  __syncthreads();
  if (t < SC_TILE) {
    float a = b2[0];
    for (int k = 0; k < DF; ++k) a = fmaf(h_lds[t][k], w2_lds[k], a);
    out[r0 + t] = a;
  }
}

// ---------------------------------------------------------------------------
// Class classifier head: relu(f @ w1 + b1) @ w2[128,17] + b2 -> out[r,17]
// ---------------------------------------------------------------------------
__global__ __launch_bounds__(256) void k_cls_class(
    const float* __restrict__ feat,
    const float* __restrict__ w1, const float* __restrict__ b1,
    const float* __restrict__ w2, const float* __restrict__ b2,
    float* __restrict__ out) {
  __shared__ float f_lds[SC_TILE][DF];
  __shared__ float h_lds[SC_TILE][DF + 1];
  __shared__ float w2_lds[DF * TT];   // 8.7 KB
  const int t = threadIdx.x;
  const int r0 = blockIdx.x * SC_TILE;
  for (int j = t; j < DF * TT; j += 256) w2_lds[j] = w2[j];
#pragma unroll
  for (int j = 0; j < 16; ++j) {
    int idx = j * 256 + t;
    int i = idx >> 7, c = idx & 127;
    f_lds[i][c] = feat[(size_t)(r0 + i) * DF + c];
  }
  __syncthreads();
  const int g = t >> 7, h = t & 127;
  float acc[16];
#pragma unroll
  for (int i = 0; i < 16; ++i) acc[i] = 0.f;
  for (int k4 = 0; k4 < DF / 4; ++k4) {
    const float wa = w1[(k4 * 4 + 0) * DF + h];
    const float wb = w1[(k4 * 4 + 1) * DF + h];
    const float wc = w1[(k4 * 4 + 2) * DF + h];
    const float wd = w1[(k4 * 4 + 3) * DF + h];
#pragma unroll
    for (int i = 0; i < 16; ++i) {
      const float4 m = *reinterpret_cast<const float4*>(&f_lds[2 * i + g][k4 * 4]);
      acc[i] = fmaf(m.x, wa, fmaf(m.y, wb, fmaf(m.z, wc, fmaf(m.w, wd, acc[i]))));
    }
  }
  const float bb = b1[h];
#pragma unroll
  for (int i = 0; i < 16; ++i) h_lds[2 * i + g][h] = fmaxf(acc[i] + bb, 0.f);
  __syncthreads();
  for (int o = t; o < SC_TILE * TT; o += 256) {
    const int i = o / TT, c = o % TT;
    float a = b2[c];
    for (int k = 0; k < DF; ++k) a = fmaf(h_lds[i][k], w2_lds[k * TT + c], a);
    out[(size_t)(r0 + i) * TT + c] = a;
  }
}

// ---------------------------------------------------------------------------
__global__ void k_copy4(const float* __restrict__ src, float* __restrict__ dst,
                        int n4) {
  int i = blockIdx.x * blockDim.x + threadIdx.x;
  if (i < n4)
    reinterpret_cast<float4*>(dst)[i] = reinterpret_cast<const float4*>(src)[i];
}

// ---------------------------------------------------------------------------
extern "C" void kernel_launch(void* const* d_in, const int* in_sizes, int n_in,
                              void* d_out, int out_size, void* d_ws,
                              size_t ws_size, hipStream_t stream) {
  (void)in_sizes; (void)n_in; (void)out_size; (void)ws_size;
  const float* x         = (const float*)d_in[0];
  const float* edge_attr = (const float*)d_in[1];
  const int*   edge_idx  = (const int*)d_in[2];
  const int*   node_ty   = (const int*)d_in[3];
  const float* ne_w1 = (const float*)d_in[4];
  const float* ne_b1 = (const float*)d_in[5];
  const float* ne_w2 = (const float*)d_in[6];
  const float* ne_b2 = (const float*)d_in[7];
  const float* ee_w1 = (const float*)d_in[8];
  const float* ee_b1 = (const float*)d_in[9];
  const float* ee_w2 = (const float*)d_in[10];
  const float* ee_b2 = (const float*)d_in[11];
  const float* me_w1 = (const float*)d_in[12];
  const float* me_b1 = (const float*)d_in[13];
  const float* me_w2 = (const float*)d_in[14];
  const float* me_b2 = (const float*)d_in[15];
  const float* mn_w1 = (const float*)d_in[16];
  const float* mn_b1 = (const float*)d_in[17];
  const float* ec_w1 = (const float*)d_in[18];
  const float* ec_b1 = (const float*)d_in[19];
  const float* ec_w2 = (const float*)d_in[20];
  const float* ec_b2 = (const float*)d_in[21];
  const float* nc_w1 = (const float*)d_in[22];
  const float* nc_b1 = (const float*)d_in[23];
  const float* nc_w2 = (const float*)d_in[24];
  const float* nc_b2 = (const float*)d_in[25];
  const float* cc_w1 = (const float*)d_in[26];
  const float* cc_b1 = (const float*)d_in[27];
  const float* cc_w2 = (const float*)d_in[28];
  const float* cc_b2 = (const float*)d_in[29];

  const int* srcv = edge_idx;            // edge_index[0]
  const int* dstv = edge_idx + N_EDGES;  // edge_index[1]

  // workspace layout (fp32): nf0 | ef0 | nf | agg | ef   (~195 MB)
  float* nf0 = (float*)d_ws;
  float* ef0 = nf0 + (size_t)N_NODES * DF;
  float* nfb = ef0 + (size_t)N_EDGES * DF;
  float* agg = nfb + (size_t)N_NODES * DF;
  float* efb = agg + (size_t)N_NODES * DF;

  // output layout: pred_edge [E] | pred_node [N] | pred_class [N,17] | nf | ef
  float* out_pe = (float*)d_out;
  float* out_pn = out_pe + N_EDGES;
  float* out_pc = out_pn + N_NODES;
  float* out_nf = out_pc + (size_t)N_NODES * TT;
  float* out_ef = out_nf + (size_t)N_NODES * DF;

  k_node_embed<<<N_NODES / 2, 256, 0, stream>>>(x, node_ty, ne_w1, ne_b1,
                                                ne_w2, ne_b2, nf0);
  k_edge_embed<<<N_EDGES / EB_TILE, 256, 0, stream>>>(edge_attr, ee_w1, ee_b1,
                                                      ee_w2, ee_b2, ef0);

  // ---- mp step 1 (nf = nf0, ef = ef0) ----
  hipMemsetAsync(agg, 0, (size_t)N_NODES * DF * sizeof(float), stream);
  k_edge_mlp<<<N_EDGES / EM_TILE, 256, 0, stream>>>(
      nf0, nf0, ef0, ef0, efb, agg, srcv, dstv, me_w1, me_b1, me_w2, me_b2);
  k_node_update<<<N_NODES / NU_TILE, 256, 0, stream>>>(nf0, nf0, agg, nfb,
                                                       mn_w1, mn_b1);
  // ---- mp step 2 ----
  hipMemsetAsync(agg, 0, (size_t)N_NODES * DF * sizeof(float), stream);
  k_edge_mlp<<<N_EDGES / EM_TILE, 256, 0, stream>>>(
      nf0, nfb, ef0, efb, efb, agg, srcv, dstv, me_w1, me_b1, me_w2, me_b2);
  k_node_update<<<N_NODES / NU_TILE, 256, 0, stream>>>(nf0, nfb, agg, nfb,
                                                       mn_w1, mn_b1);
  // pred_edge from ef after 2 edge steps
  k_cls_scalar<<<N_EDGES / SC_TILE, 256, 0, stream>>>(efb, ec_w1, ec_b1, ec_w2,
                                                      ec_b2, out_pe);
  // ---- mp step 3 ----
  hipMemsetAsync(agg, 0, (size_t)N_NODES * DF * sizeof(float), stream);
  k_edge_mlp<<<N_EDGES / EM_TILE, 256, 0, stream>>>(
      nf0, nfb, ef0, efb, efb, agg, srcv, dstv, me_w1, me_b1, me_w2, me_b2);
  k_node_update<<<N_NODES / NU_TILE, 256, 0, stream>>>(nf0, nfb, agg, nfb,
                                                       mn_w1, mn_b1);

  // heads + feature outputs
  k_cls_scalar<<<N_NODES / SC_TILE, 256, 0, stream>>>(nfb, nc_w1, nc_b1, nc_w2,
                                                      nc_b2, out_pn);
  k_cls_class<<<N_NODES / SC_TILE, 256, 0, stream>>>(nfb, cc_w1, cc_b1, cc_w2,
                                                     cc_b2, out_pc);
  {
    int n4 = N_NODES * DF / 4;
    k_copy4<<<(n4 + 255) / 256, 256, 0, stream>>>(nfb, out_nf, n4);
  }
  {
    int n4 = N_EDGES * DF / 4;
    k_copy4<<<(n4 + 255) / 256, 256, 0, stream>>>(efb, out_ef, n4);
  }
}

// Round 2
// 1323.861 us; speedup vs baseline: 4.1112x; 4.1112x over previous
//
#include <hip/hip_runtime.h>
#include <hip/hip_bf16.h>

#define N_NODES 20000
#define N_EDGES 160000
#define DIN_NODE 256
#define DIN_EDGE 64
#define DF 128      // feature dim
#define HH 256      // edge-MLP hidden dim
#define TT 17       // node types

typedef __attribute__((ext_vector_type(8))) short short8v;   // 8 bf16 (4 VGPRs)
typedef __attribute__((ext_vector_type(4))) float f32x4;     // MFMA C/D frag

// fp32 -> bf16 round-to-nearest-even (data has no NaN)
__device__ __forceinline__ unsigned short f2bf(float f) {
  unsigned int u = __builtin_bit_cast(unsigned int, f);
  u += 0x7FFFu + ((u >> 16) & 1u);
  return (unsigned short)(u >> 16);
}

// ---------------------------------------------------------------------------
// Pack fp32 weight [K][N] into MFMA B-fragment order: [kt][nt][lane][8] bf16,
// where frag elem j of lane l = W[kt*32 + 8*(l>>4) + j][nt*16 + (l&15)].
// ---------------------------------------------------------------------------
__global__ __launch_bounds__(256) void k_pack_w(
    const float* __restrict__ w, unsigned short* __restrict__ out,
    int Kdim, int Ndim) {
  const int tile = blockIdx.x * 4 + (threadIdx.x >> 6);
  const int l = threadIdx.x & 63;
  const int ntTiles = Ndim >> 4;
  const int total = (Kdim >> 5) * ntTiles;
  if (tile >= total) return;
  const int kt = tile / ntTiles, nt = tile % ntTiles;
  const int col = (nt << 4) + (l & 15);
  const int k0 = (kt << 5) + ((l >> 4) << 3);
  unsigned short* o = out + (((size_t)tile << 6) + l) * 8;
#pragma unroll
  for (int j = 0; j < 8; ++j) o[j] = f2bf(w[(size_t)(k0 + j) * Ndim + col]);
}

// ---------------------------------------------------------------------------
// Node embedding: type-routed 2-layer MLP 256 -> 128 (relu) -> 128.
// ---------------------------------------------------------------------------
__global__ __launch_bounds__(256) void k_node_embed(
    const float* __restrict__ x, const int* __restrict__ types,
    const float* __restrict__ w1, const float* __restrict__ b1,
    const float* __restrict__ w2, const float* __restrict__ b2,
    float* __restrict__ nf0) {
  __shared__ float x_lds[2][DIN_NODE];
  __shared__ float h_lds[2][DF];
  const int t = threadIdx.x;
  const int g = t >> 7, h = t & 127;
  const int n0 = blockIdx.x * 2;
  x_lds[0][t] = x[(size_t)n0 * DIN_NODE + t];
  x_lds[1][t] = x[(size_t)(n0 + 1) * DIN_NODE + t];
  __syncthreads();
  const int n = n0 + g;
  const int ty = types[n];
  const float* W1 = w1 + (size_t)ty * DIN_NODE * DF;
  float acc = b1[ty * DF + h];
  for (int k = 0; k < DIN_NODE; ++k)
    acc = fmaf(x_lds[g][k], W1[k * DF + h], acc);
  h_lds[g][h] = fmaxf(acc, 0.f);
  __syncthreads();
  const float* W2 = w2 + (size_t)ty * DF * DF;
  float acc2 = b2[ty * DF + h];
  for (int k = 0; k < DF; ++k)
    acc2 = fmaf(h_lds[g][k], W2[k * DF + h], acc2);
  nf0[(size_t)n * DF + h] = acc2;
}

// ---------------------------------------------------------------------------
// Edge embedding: 64 -> 128 (relu) -> 128.  Block = 256 threads, 32 edges.
// ---------------------------------------------------------------------------
#define EB_TILE 32
__global__ __launch_bounds__(256) void k_edge_embed(
    const float* __restrict__ ea,
    const float* __restrict__ w1, const float* __restrict__ b1,
    const float* __restrict__ w2, const float* __restrict__ b2,
    float* __restrict__ ef0) {
  __shared__ float a_lds[EB_TILE][DIN_EDGE];
  __shared__ float h_lds[EB_TILE][DF];
  const int t = threadIdx.x;
  const int e0 = blockIdx.x * EB_TILE;
#pragma unroll
  for (int j = 0; j < 8; ++j) {
    int idx = j * 256 + t;
    int i = idx >> 6, c = idx & 63;
    a_lds[i][c] = ea[(size_t)(e0 + i) * DIN_EDGE + c];
  }
  __syncthreads();
  const int g = t >> 7, h = t & 127;
  float acc[16];
#pragma unroll
  for (int i = 0; i < 16; ++i) acc[i] = 0.f;
  for (int k4 = 0; k4 < DIN_EDGE / 4; ++k4) {
    const float wa = w1[(k4 * 4 + 0) * DF + h];
    const float wb = w1[(k4 * 4 + 1) * DF + h];
    const float wc = w1[(k4 * 4 + 2) * DF + h];
    const float wd = w1[(k4 * 4 + 3) * DF + h];
#pragma unroll
    for (int i = 0; i < 16; ++i) {
      const float4 m = *reinterpret_cast<const float4*>(&a_lds[2 * i + g][k4 * 4]);
      acc[i] = fmaf(m.x, wa, fmaf(m.y, wb, fmaf(m.z, wc, fmaf(m.w, wd, acc[i]))));
    }
  }
  const float bb = b1[h];
#pragma unroll
  for (int i = 0; i < 16; ++i) h_lds[2 * i + g][h] = fmaxf(acc[i] + bb, 0.f);
  __syncthreads();
  float acc2[16];
#pragma unroll
  for (int i = 0; i < 16; ++i) acc2[i] = 0.f;
  for (int k4 = 0; k4 < DF / 4; ++k4) {
    const float wa = w2[(k4 * 4 + 0) * DF + h];
    const float wb = w2[(k4 * 4 + 1) * DF + h];
    const float wc = w2[(k4 * 4 + 2) * DF + h];
    const float wd = w2[(k4 * 4 + 3) * DF + h];
#pragma unroll
    for (int i = 0; i < 16; ++i) {
      const float4 m = *reinterpret_cast<const float4*>(&h_lds[2 * i + g][k4 * 4]);
      acc2[i] = fmaf(m.x, wa, fmaf(m.y, wb, fmaf(m.z, wc, fmaf(m.w, wd, acc2[i]))));
    }
  }
  const float b2v = b2[h];
#pragma unroll
  for (int i = 0; i < 16; ++i)
    ef0[(size_t)(e0 + 2 * i + g) * DF + h] = acc2[i] + b2v;
}

// ---------------------------------------------------------------------------
// Edge MLP via MFMA.  Block = 256 threads (4 waves), 32 edges.
// A tile (32x768 bf16, XOR-swizzled) in LDS; hidden reuses the same LDS.
// Weights pre-packed in fragment order (k_pack_w).  fp32 accumulate.
// ---------------------------------------------------------------------------
#define EM_TILE 32
__global__ __launch_bounds__(256) void k_edge_mlp_mfma(
    const float* __restrict__ nf0, const float* __restrict__ nf,
    const float* __restrict__ ef0, const float* __restrict__ ef_in,
    float* __restrict__ ef_out, float* __restrict__ agg,
    const int* __restrict__ srcv, const int* __restrict__ dstv,
    const unsigned short* __restrict__ wp1, const float* __restrict__ b1,
    const unsigned short* __restrict__ wp2, const float* __restrict__ b2) {
  __shared__ __align__(16) unsigned char A_lds[EM_TILE * 768 * 2];  // 48 KB
  __shared__ int sd[2][EM_TILE];
  const int t = threadIdx.x;
  const int e0 = blockIdx.x * EM_TILE;
  if (t < EM_TILE) sd[0][t] = srcv[e0 + t];
  else if (t < 2 * EM_TILE) sd[1][t - EM_TILE] = dstv[e0 + t - EM_TILE];
  __syncthreads();

  // ---- gather 32 x [nf0[dst]|nf[dst]|nf0[src]|nf[src]|ef0|ef] -> bf16 LDS ---
  // 6144 float4 quads: quad = (q&31), seg = q>>5, edge i = seg/6, part p = seg%6
#pragma unroll
  for (int j = 0; j < 24; ++j) {
    const int q = j * 256 + t;
    const int quad = q & 31;
    const int seg = q >> 5;
    const int i = seg / 6;
    const int p = seg - 6 * i;
    const float* bp;
    switch (p) {
      case 0: bp = nf0 + (size_t)sd[1][i] * DF; break;
      case 1: bp = nf + (size_t)sd[1][i] * DF; break;
      case 2: bp = nf0 + (size_t)sd[0][i] * DF; break;
      case 3: bp = nf + (size_t)sd[0][i] * DF; break;
      case 4: bp = ef0 + (size_t)(e0 + i) * DF; break;
      default: bp = ef_in + (size_t)(e0 + i) * DF; break;
    }
    const float4 v = *reinterpret_cast<const float4*>(bp + (quad << 2));
    ushort4 o;
    o.x = f2bf(v.x); o.y = f2bf(v.y); o.z = f2bf(v.z); o.w = f2bf(v.w);
    const int boff = (i * 1536 + p * 256 + quad * 8) ^ ((i & 7) << 4);
    *reinterpret_cast<ushort4*>(A_lds + boff) = o;
  }
  __syncthreads();

  const int w = t >> 6;        // wave 0..3
  const int l = t & 63;        // lane
  const int lr = l & 15;       // row/col within 16-tile
  const int lg = l >> 4;       // k-group

  // ---- layer 1: [32x768] @ [768x256] -> hidden, wave w owns n-tiles 4w..4w+3
  f32x4 acc[2][4];
#pragma unroll
  for (int mt = 0; mt < 2; ++mt)
#pragma unroll
    for (int q = 0; q < 4; ++q)
#pragma unroll
      for (int r = 0; r < 4; ++r) acc[mt][q][r] = 0.f;

  const int r0 = lr, r1 = 16 + lr;
  const int off0base = (r0 * 1536 + lg * 16);
  const int off1base = (r1 * 1536 + lg * 16);
  const int sw0 = (r0 & 7) << 4, sw1 = (r1 & 7) << 4;
#pragma unroll 2
  for (int kt = 0; kt < 24; ++kt) {
    const short8v a0 = *reinterpret_cast<const short8v*>(
        A_lds + ((off0base + kt * 64) ^ sw0));
    const short8v a1 = *reinterpret_cast<const short8v*>(
        A_lds + ((off1base + kt * 64) ^ sw1));
    short8v b[4];
#pragma unroll
    for (int q = 0; q < 4; ++q)
      b[q] = *reinterpret_cast<const short8v*>(
          wp1 + (((size_t)(kt * 16 + 4 * w + q) * 64 + l) << 3));
#pragma unroll
    for (int q = 0; q < 4; ++q) {
      acc[0][q] = __builtin_amdgcn_mfma_f32_16x16x32_bf16(a0, b[q], acc[0][q], 0, 0, 0);
      acc[1][q] = __builtin_amdgcn_mfma_f32_16x16x32_bf16(a1, b[q], acc[1][q], 0, 0, 0);
    }
  }
  __syncthreads();   // everyone done reading A_lds

  // ---- epilogue 1: bias + relu -> bf16 hidden [32][256] (swizzled, reuses LDS)
#pragma unroll
  for (int q = 0; q < 4; ++q) {
    const int col = (4 * w + q) * 16 + lr;
    const float bias = b1[col];
#pragma unroll
    for (int mt = 0; mt < 2; ++mt)
#pragma unroll
      for (int r = 0; r < 4; ++r) {
        const int row = mt * 16 + lg * 4 + r;
        const unsigned short hv = f2bf(fmaxf(acc[mt][q][r] + bias, 0.f));
        *reinterpret_cast<unsigned short*>(
            A_lds + ((row * 512 + col * 2) ^ ((row & 7) << 4))) = hv;
      }
  }
  __syncthreads();

  // ---- layer 2: [32x256] @ [256x128], wave w owns n-tiles 2w, 2w+1 ----------
  f32x4 acc2[2][2];
#pragma unroll
  for (int mt = 0; mt < 2; ++mt)
#pragma unroll
    for (int q = 0; q < 2; ++q)
#pragma unroll
      for (int r = 0; r < 4; ++r) acc2[mt][q][r] = 0.f;

  const int hoff0 = (r0 * 512 + lg * 16);
  const int hoff1 = (r1 * 512 + lg * 16);
#pragma unroll
  for (int kt = 0; kt < 8; ++kt) {
    const short8v a0 = *reinterpret_cast<const short8v*>(
        A_lds + ((hoff0 + kt * 64) ^ sw0));
    const short8v a1 = *reinterpret_cast<const short8v*>(
        A_lds + ((hoff1 + kt * 64) ^ sw1));
    short8v b[2];
#pragma unroll
    for (int q = 0; q < 2; ++q)
      b[q] = *reinterpret_cast<const short8v*>(
          wp2 + (((size_t)(kt * 8 + 2 * w + q) * 64 + l) << 3));
#pragma unroll
    for (int q = 0; q < 2; ++q) {
      acc2[0][q] = __builtin_amdgcn_mfma_f32_16x16x32_bf16(a0, b[q], acc2[0][q], 0, 0, 0);
      acc2[1][q] = __builtin_amdgcn_mfma_f32_16x16x32_bf16(a1, b[q], acc2[1][q], 0, 0, 0);
    }
  }

  // ---- epilogue 2: bias, store ef, atomic agg[dst] --------------------------
#pragma unroll
  for (int q = 0; q < 2; ++q) {
    const int n = (2 * w + q) * 16 + lr;
    const float bias = b2[n];
#pragma unroll
    for (int mt = 0; mt < 2; ++mt)
#pragma unroll
      for (int r = 0; r < 4; ++r) {
        const int m = mt * 16 + lg * 4 + r;
        const float v = acc2[mt][q][r] + bias;
        ef_out[(size_t)(e0 + m) * DF + n] = v;
        atomicAdd(&agg[(size_t)sd[1][m] * DF + n], v);
      }
  }
}

// ---------------------------------------------------------------------------
// Node update: nf_new = [nf0 | nf | agg] (384) @ w (384x128) + b.
// ---------------------------------------------------------------------------
#define NU_TILE 16
__global__ __launch_bounds__(256) void k_node_update(
    const float* __restrict__ nf0, const float* __restrict__ nf_in,
    const float* __restrict__ agg, float* __restrict__ nf_out,
    const float* __restrict__ w, const float* __restrict__ b) {
  __shared__ float c_lds[NU_TILE][3 * DF];
  const int t = threadIdx.x;
  const int n0 = blockIdx.x * NU_TILE;
  const int g = t >> 7, lane = t & 127;
  for (int j = 0; j < 24; ++j) {
    const int s = 2 * j + g;
    const int i = s / 3, p = s % 3;
    const float* base = (p == 0) ? nf0 + (size_t)(n0 + i) * DF
                      : (p == 1) ? nf_in + (size_t)(n0 + i) * DF
                                 : agg + (size_t)(n0 + i) * DF;
    c_lds[i][p * DF + lane] = base[lane];
  }
  __syncthreads();
  float acc[8];
#pragma unroll
  for (int i = 0; i < 8; ++i) acc[i] = 0.f;
  for (int k4 = 0; k4 < (3 * DF) / 4; ++k4) {
    const float wa = w[(k4 * 4 + 0) * DF + lane];
    const float wb = w[(k4 * 4 + 1) * DF + lane];
    const float wc = w[(k4 * 4 + 2) * DF + lane];
    const float wd = w[(k4 * 4 + 3) * DF + lane];
#pragma unroll
    for (int i = 0; i < 8; ++i) {
      const float4 m = *reinterpret_cast<const float4*>(&c_lds[2 * i + g][k4 * 4]);
      acc[i] = fmaf(m.x, wa, fmaf(m.y, wb, fmaf(m.z, wc, fmaf(m.w, wd, acc[i]))));
    }
  }
  const float bv = b[lane];
#pragma unroll
  for (int i = 0; i < 8; ++i)
    nf_out[(size_t)(n0 + 2 * i + g) * DF + lane] = acc[i] + bv;
}

// ---------------------------------------------------------------------------
// Scalar classifier head.
// ---------------------------------------------------------------------------
#define SC_TILE 32
__global__ __launch_bounds__(256) void k_cls_scalar(
    const float* __restrict__ feat,
    const float* __restrict__ w1, const float* __restrict__ b1,
    const float* __restrict__ w2, const float* __restrict__ b2,
    float* __restrict__ out) {
  __shared__ float f_lds[SC_TILE][DF];
  __shared__ float h_lds[SC_TILE][DF + 1];
  __shared__ float w2_lds[DF];
  const int t = threadIdx.x;
  const int r0 = blockIdx.x * SC_TILE;
  if (t < DF) w2_lds[t] = w2[t];
#pragma unroll
  for (int j = 0; j < 16; ++j) {
    int idx = j * 256 + t;
    int i = idx >> 7, c = idx & 127;
    f_lds[i][c] = feat[(size_t)(r0 + i) * DF + c];
  }
  __syncthreads();
  const int g = t >> 7, h = t & 127;
  float acc[16];
#pragma unroll
  for (int i = 0; i < 16; ++i) acc[i] = 0.f;
  for (int k4 = 0; k4 < DF / 4; ++k4) {
    const float wa = w1[(k4 * 4 + 0) * DF + h];
    const float wb = w1[(k4 * 4 + 1) * DF + h];
    const float wc = w1[(k4 * 4 + 2) * DF + h];
    const float wd = w1[(k4 * 4 + 3) * DF + h];
#pragma unroll
    for (int i = 0; i < 16; ++i) {
      const float4 m = *reinterpret_cast<const float4*>(&f_lds[2 * i + g][k4 * 4]);
      acc[i] = fmaf(m.x, wa, fmaf(m.y, wb, fmaf(m.z, wc, fmaf(m.w, wd, acc[i]))));
    }
  }
  const float bb = b1[h];
#pragma unroll
  for (int i = 0; i < 16; ++i) h_lds[2 * i + g][h] = fmaxf(acc[i] + bb, 0.f);
  __syncthreads();
  if (t < SC_TILE) {
    float a = b2[0];
    for (int k = 0; k < DF; ++k) a = fmaf(h_lds[t][k], w2_lds[k], a);
    out[r0 + t] = a;
  }
}

// ---------------------------------------------------------------------------
// Class classifier head (out dim 17).
// ---------------------------------------------------------------------------
__global__ __launch_bounds__(256) void k_cls_class(
    const float* __restrict__ feat,
    const float* __restrict__ w1, const float* __restrict__ b1,
    const float* __restrict__ w2, const float* __restrict__ b2,
    float* __restrict__ out) {
  __shared__ float f_lds[SC_TILE][DF];
  __shared__ float h_lds[SC_TILE][DF + 1];
  __shared__ float w2_lds[DF * TT];
  const int t = threadIdx.x;
  const int r0 = blockIdx.x * SC_TILE;
  for (int j = t; j < DF * TT; j += 256) w2_lds[j] = w2[j];
#pragma unroll
  for (int j = 0; j < 16; ++j) {
    int idx = j * 256 + t;
    int i = idx >> 7, c = idx & 127;
    f_lds[i][c] = feat[(size_t)(r0 + i) * DF + c];
  }
  __syncthreads();
  const int g = t >> 7, h = t & 127;
  float acc[16];
#pragma unroll
  for (int i = 0; i < 16; ++i) acc[i] = 0.f;
  for (int k4 = 0; k4 < DF / 4; ++k4) {
    const float wa = w1[(k4 * 4 + 0) * DF + h];
    const float wb = w1[(k4 * 4 + 1) * DF + h];
    const float wc = w1[(k4 * 4 + 2) * DF + h];
    const float wd = w1[(k4 * 4 + 3) * DF + h];
#pragma unroll
    for (int i = 0; i < 16; ++i) {
      const float4 m = *reinterpret_cast<const float4*>(&f_lds[2 * i + g][k4 * 4]);
      acc[i] = fmaf(m.x, wa, fmaf(m.y, wb, fmaf(m.z, wc, fmaf(m.w, wd, acc[i]))));
    }
  }
  const float bb = b1[h];
#pragma unroll
  for (int i = 0; i < 16; ++i) h_lds[2 * i + g][h] = fmaxf(acc[i] + bb, 0.f);
  __syncthreads();
  for (int o = t; o < SC_TILE * TT; o += 256) {
    const int i = o / TT, c = o % TT;
    float a = b2[c];
    for (int k = 0; k < DF; ++k) a = fmaf(h_lds[i][k], w2_lds[k * TT + c], a);
    out[(size_t)(r0 + i) * TT + c] = a;
  }
}

// ---------------------------------------------------------------------------
extern "C" void kernel_launch(void* const* d_in, const int* in_sizes, int n_in,
                              void* d_out, int out_size, void* d_ws,
                              size_t ws_size, hipStream_t stream) {
  (void)in_sizes; (void)n_in; (void)out_size; (void)ws_size;
  const float* x         = (const float*)d_in[0];
  const float* edge_attr = (const float*)d_in[1];
  const int*   edge_idx  = (const int*)d_in[2];
  const int*   node_ty   = (const int*)d_in[3];
  const float* ne_w1 = (const float*)d_in[4];
  const float* ne_b1 = (const float*)d_in[5];
  const float* ne_w2 = (const float*)d_in[6];
  const float* ne_b2 = (const float*)d_in[7];
  const float* ee_w1 = (const float*)d_in[8];
  const float* ee_b1 = (const float*)d_in[9];
  const float* ee_w2 = (const float*)d_in[10];
  const float* ee_b2 = (const float*)d_in[11];
  const float* me_w1 = (const float*)d_in[12];
  const float* me_b1 = (const float*)d_in[13];
  const float* me_w2 = (const float*)d_in[14];
  const float* me_b2 = (const float*)d_in[15];
  const float* mn_w1 = (const float*)d_in[16];
  const float* mn_b1 = (const float*)d_in[17];
  const float* ec_w1 = (const float*)d_in[18];
  const float* ec_b1 = (const float*)d_in[19];
  const float* ec_w2 = (const float*)d_in[20];
  const float* ec_b2 = (const float*)d_in[21];
  const float* nc_w1 = (const float*)d_in[22];
  const float* nc_b1 = (const float*)d_in[23];
  const float* nc_w2 = (const float*)d_in[24];
  const float* nc_b2 = (const float*)d_in[25];
  const float* cc_w1 = (const float*)d_in[26];
  const float* cc_b1 = (const float*)d_in[27];
  const float* cc_w2 = (const float*)d_in[28];
  const float* cc_b2 = (const float*)d_in[29];

  const int* srcv = edge_idx;            // edge_index[0]
  const int* dstv = edge_idx + N_EDGES;  // edge_index[1]

  // workspace: nf0 | ef0 | agg | wpack1 | wpack2   (~103 MB)
  float* nf0 = (float*)d_ws;
  float* ef0 = nf0 + (size_t)N_NODES * DF;
  float* agg = ef0 + (size_t)N_EDGES * DF;
  unsigned short* wp1 = (unsigned short*)(agg + (size_t)N_NODES * DF);
  unsigned short* wp2 = wp1 + (size_t)24 * 16 * 64 * 8;   // 768x256 packed

  // output layout: pred_edge [E] | pred_node [N] | pred_class [N,17] | nf | ef
  float* out_pe = (float*)d_out;
  float* out_pn = out_pe + N_EDGES;
  float* out_pc = out_pn + N_NODES;
  float* nfb = out_pc + (size_t)N_NODES * TT;     // nf ping-pong lives in d_out
  float* efb = nfb + (size_t)N_NODES * DF;        // ef ping-pong lives in d_out

  // pack edge-MLP weights to bf16 fragment order (once per launch)
  k_pack_w<<<96, 256, 0, stream>>>(me_w1, wp1, 6 * DF, HH);   // 384 tiles
  k_pack_w<<<16, 256, 0, stream>>>(me_w2, wp2, HH, DF);       // 64 tiles

  k_node_embed<<<N_NODES / 2, 256, 0, stream>>>(x, node_ty, ne_w1, ne_b1,
                                                ne_w2, ne_b2, nf0);
  k_edge_embed<<<N_EDGES / EB_TILE, 256, 0, stream>>>(edge_attr, ee_w1, ee_b1,
                                                      ee_w2, ee_b2, ef0);

  // ---- mp step 1 (nf = nf0, ef = ef0) ----
  hipMemsetAsync(agg, 0, (size_t)N_NODES * DF * sizeof(float), stream);
  k_edge_mlp_mfma<<<N_EDGES / EM_TILE, 256, 0, stream>>>(
      nf0, nf0, ef0, ef0, efb, agg, srcv, dstv, wp1, me_b1, wp2, me_b2);
  k_node_update<<<N_NODES / NU_TILE, 256, 0, stream>>>(nf0, nf0, agg, nfb,
                                                       mn_w1, mn_b1);
  // ---- mp step 2 ----
  hipMemsetAsync(agg, 0, (size_t)N_NODES * DF * sizeof(float), stream);
  k_edge_mlp_mfma<<<N_EDGES / EM_TILE, 256, 0, stream>>>(
      nf0, nfb, ef0, efb, efb, agg, srcv, dstv, wp1, me_b1, wp2, me_b2);
  k_node_update<<<N_NODES / NU_TILE, 256, 0, stream>>>(nf0, nfb, agg, nfb,
                                                       mn_w1, mn_b1);
  // pred_edge from ef after 2 edge steps
  k_cls_scalar<<<N_EDGES / SC_TILE, 256, 0, stream>>>(efb, ec_w1, ec_b1, ec_w2,
                                                      ec_b2, out_pe);
  // ---- mp step 3 ----
  hipMemsetAsync(agg, 0, (size_t)N_NODES * DF * sizeof(float), stream);
  k_edge_mlp_mfma<<<N_EDGES / EM_TILE, 256, 0, stream>>>(
      nf0, nfb, ef0, efb, efb, agg, srcv, dstv, wp1, me_b1, wp2, me_b2);
  k_node_update<<<N_NODES / NU_TILE, 256, 0, stream>>>(nf0, nfb, agg, nfb,
                                                       mn_w1, mn_b1);

  // heads (nf/ef already live in d_out)
  k_cls_scalar<<<N_NODES / SC_TILE, 256, 0, stream>>>(nfb, nc_w1, nc_b1, nc_w2,
                                                      nc_b2, out_pn);
  k_cls_class<<<N_NODES / SC_TILE, 256, 0, stream>>>(nfb, cc_w1, cc_b1, cc_w2,
                                                     cc_b2, out_pc);
}

// Round 3
// 801.408 us; speedup vs baseline: 6.7914x; 1.6519x over previous
//
#include <hip/hip_runtime.h>
#include <hip/hip_bf16.h>

#define N_NODES 20000
#define N_EDGES 160000
#define DIN_NODE 256
#define DIN_EDGE 64
#define DF 128      // feature dim
#define HH 256      // edge-MLP hidden dim
#define TT 17       // node types
#define NE_PAD_SLOTS 20544   // 642 blocks * 32 (type-padded bucket list)

typedef __attribute__((ext_vector_type(8))) short short8v;   // 8 bf16
typedef __attribute__((ext_vector_type(4))) float f32x4;     // MFMA C/D frag
typedef unsigned short ushort_t;

// fp32 -> bf16 round-to-nearest-even
__device__ __forceinline__ unsigned short f2bf(float f) {
  unsigned int u = __builtin_bit_cast(unsigned int, f);
  u += 0x7FFFu + ((u >> 16) & 1u);
  return (unsigned short)(u >> 16);
}

__device__ __forceinline__ short8v pack8(float4 a, float4 b) {
  short8v o;
  o[0] = (short)f2bf(a.x); o[1] = (short)f2bf(a.y);
  o[2] = (short)f2bf(a.z); o[3] = (short)f2bf(a.w);
  o[4] = (short)f2bf(b.x); o[5] = (short)f2bf(b.y);
  o[6] = (short)f2bf(b.z); o[7] = (short)f2bf(b.w);
  return o;
}

// ---------------------------------------------------------------------------
// Pack fp32 weight [batch][K][N] into MFMA B-fragment order:
// tile = b*(K/32)*(N/16) + kt*(N/16) + nt; elem j of lane l =
// W[b][kt*32 + 8*(l>>4) + j][nt*16 + (l&15)].
// ---------------------------------------------------------------------------
__global__ __launch_bounds__(256) void k_pack_w(
    const float* __restrict__ w, unsigned short* __restrict__ out,
    int Kdim, int Ndim, int batch) {
  const int tile = blockIdx.x * 4 + (threadIdx.x >> 6);
  const int l = threadIdx.x & 63;
  const int ntTiles = Ndim >> 4;
  const int tilesPer = (Kdim >> 5) * ntTiles;
  if (tile >= tilesPer * batch) return;
  const int bt = tile / tilesPer;
  const int rr = tile - bt * tilesPer;
  const int kt = rr / ntTiles, nt = rr % ntTiles;
  const float* wb = w + (size_t)bt * Kdim * Ndim;
  const int col = (nt << 4) + (l & 15);
  const int k0 = (kt << 5) + ((l >> 4) << 3);
  unsigned short* o = out + (((size_t)tile << 6) + l) * 8;
#pragma unroll
  for (int j = 0; j < 8; ++j) o[j] = f2bf(wb[(size_t)(k0 + j) * Ndim + col]);
}

// ---------------------------------------------------------------------------
// Node-type bucketing (padded segments, 32-aligned per type).
// ---------------------------------------------------------------------------
__global__ void k_count(const int* __restrict__ types, int* __restrict__ cnt) {
  const int n = blockIdx.x * 256 + threadIdx.x;
  if (n < N_NODES) atomicAdd(&cnt[types[n]], 1);
}
__global__ void k_prefix(const int* __restrict__ cnt, int* __restrict__ poff,
                         int* __restrict__ woff) {
  if (threadIdx.x == 0) {
    int cur = 0;
    for (int t = 0; t < TT; ++t) {
      poff[t] = cur; woff[t] = cur;
      cur += (cnt[t] + 31) & ~31;
    }
  }
}
__global__ void k_scatter(const int* __restrict__ types, int* __restrict__ woff,
                          int* __restrict__ bucket) {
  const int n = blockIdx.x * 256 + threadIdx.x;
  if (n < N_NODES) {
    const int pos = atomicAdd(&woff[types[n]], 1);
    bucket[pos] = n;
  }
}

// ---------------------------------------------------------------------------
// Type-batched node embedding: 32 nodes of ONE type per block.
// 256->128 relu -> 128, MFMA, output bf16 nf0b scattered by node id.
// ---------------------------------------------------------------------------
__global__ __launch_bounds__(256) void k_node_embed_mfma(
    const float* __restrict__ x, const int* __restrict__ bucket,
    const int* __restrict__ types,
    const unsigned short* __restrict__ wp1, const float* __restrict__ b1,
    const unsigned short* __restrict__ wp2, const float* __restrict__ b2,
    unsigned short* __restrict__ nf0b) {
  __shared__ __align__(16) unsigned char A[32 * 512];   // 32 x 256 bf16
  __shared__ __align__(16) unsigned char Hb[32 * 256];  // 32 x 128 bf16
  __shared__ int sn[32];
  const int t = threadIdx.x;
  const int r0 = blockIdx.x * 32;
  if (t < 32) sn[t] = bucket[r0 + t];
  __syncthreads();
  if (sn[0] < 0) return;          // whole window is padding
  const int ty = types[sn[0]];

#pragma unroll
  for (int j = 0; j < 4; ++j) {
    const int q = j * 256 + t;
    const int i = q >> 5, c = q & 31;
    const int nd = sn[i];
    short8v o;
    if (nd >= 0) {
      const float* xr = x + (size_t)nd * DIN_NODE + c * 8;
      o = pack8(*reinterpret_cast<const float4*>(xr),
                *reinterpret_cast<const float4*>(xr + 4));
    } else {
#pragma unroll
      for (int k = 0; k < 8; ++k) o[k] = 0;
    }
    *reinterpret_cast<short8v*>(A + ((i * 512 + c * 16) ^ ((i & 7) << 4))) = o;
  }
  __syncthreads();

  const int w = t >> 6, l = t & 63, lr = l & 15, lg = l >> 4;
  const int sw = (lr & 7) << 4;
  const int row0 = lr, row1 = 16 + lr;

  f32x4 acc[2][2];
#pragma unroll
  for (int mt = 0; mt < 2; ++mt)
#pragma unroll
    for (int q = 0; q < 2; ++q)
#pragma unroll
      for (int r = 0; r < 4; ++r) acc[mt][q][r] = 0.f;

#pragma unroll
  for (int kt = 0; kt < 8; ++kt) {
    const short8v a0 = *reinterpret_cast<const short8v*>(
        A + ((row0 * 512 + kt * 64 + lg * 16) ^ sw));
    const short8v a1 = *reinterpret_cast<const short8v*>(
        A + ((row1 * 512 + kt * 64 + lg * 16) ^ sw));
#pragma unroll
    for (int q = 0; q < 2; ++q) {
      const short8v bq = *reinterpret_cast<const short8v*>(
          wp1 + (((size_t)(ty * 64 + kt * 8 + 2 * w + q) * 64 + l) << 3));
      acc[0][q] = __builtin_amdgcn_mfma_f32_16x16x32_bf16(a0, bq, acc[0][q], 0, 0, 0);
      acc[1][q] = __builtin_amdgcn_mfma_f32_16x16x32_bf16(a1, bq, acc[1][q], 0, 0, 0);
    }
  }
  // hidden -> Hb (separate region, only need sync before reads)
#pragma unroll
  for (int q = 0; q < 2; ++q) {
    const int col = (2 * w + q) * 16 + lr;
    const float bias = b1[ty * DF + col];
#pragma unroll
    for (int mt = 0; mt < 2; ++mt)
#pragma unroll
      for (int r = 0; r < 4; ++r) {
        const int row = mt * 16 + lg * 4 + r;
        *reinterpret_cast<unsigned short*>(
            Hb + ((row * 256 + col * 2) ^ ((row & 7) << 4))) =
            f2bf(fmaxf(acc[mt][q][r] + bias, 0.f));
      }
  }
  __syncthreads();

  f32x4 acc2[2][2];
#pragma unroll
  for (int mt = 0; mt < 2; ++mt)
#pragma unroll
    for (int q = 0; q < 2; ++q)
#pragma unroll
      for (int r = 0; r < 4; ++r) acc2[mt][q][r] = 0.f;
#pragma unroll
  for (int kt = 0; kt < 4; ++kt) {
    const short8v a0 = *reinterpret_cast<const short8v*>(
        Hb + ((row0 * 256 + kt * 64 + lg * 16) ^ sw));
    const short8v a1 = *reinterpret_cast<const short8v*>(
        Hb + ((row1 * 256 + kt * 64 + lg * 16) ^ sw));
#pragma unroll
    for (int q = 0; q < 2; ++q) {
      const short8v bq = *reinterpret_cast<const short8v*>(
          wp2 + (((size_t)(ty * 32 + kt * 8 + 2 * w + q) * 64 + l) << 3));
      acc2[0][q] = __builtin_amdgcn_mfma_f32_16x16x32_bf16(a0, bq, acc2[0][q], 0, 0, 0);
      acc2[1][q] = __builtin_amdgcn_mfma_f32_16x16x32_bf16(a1, bq, acc2[1][q], 0, 0, 0);
    }
  }
#pragma unroll
  for (int q = 0; q < 2; ++q) {
    const int col = (2 * w + q) * 16 + lr;
    const float bias = b2[ty * DF + col];
#pragma unroll
    for (int mt = 0; mt < 2; ++mt)
#pragma unroll
      for (int r = 0; r < 4; ++r) {
        const int row = mt * 16 + lg * 4 + r;
        const int nd = sn[row];
        if (nd >= 0)
          nf0b[(size_t)nd * DF + col] = f2bf(acc2[mt][q][r] + bias);
      }
  }
}

// ---------------------------------------------------------------------------
// Edge embedding MFMA: 64 -> 128 relu -> 128, 32 edges/block, bf16 out.
// ---------------------------------------------------------------------------
__global__ __launch_bounds__(256) void k_edge_embed_mfma(
    const float* __restrict__ ea,
    const unsigned short* __restrict__ wp1, const float* __restrict__ b1,
    const unsigned short* __restrict__ wp2, const float* __restrict__ b2,
    unsigned short* __restrict__ ef0b) {
  __shared__ __align__(16) unsigned char A[32 * 128];   // 32 x 64 bf16
  __shared__ __align__(16) unsigned char Hb[32 * 256];  // 32 x 128 bf16
  const int t = threadIdx.x;
  const int e0 = blockIdx.x * 32;
  {
    const int i = t >> 3, c = t & 7;
    const float* xr = ea + (size_t)(e0 + i) * DIN_EDGE + c * 8;
    const short8v o = pack8(*reinterpret_cast<const float4*>(xr),
                            *reinterpret_cast<const float4*>(xr + 4));
    *reinterpret_cast<short8v*>(A + ((i * 128 + c * 16) ^ ((i & 7) << 4))) = o;
  }
  __syncthreads();

  const int w = t >> 6, l = t & 63, lr = l & 15, lg = l >> 4;
  const int sw = (lr & 7) << 4;
  const int row0 = lr, row1 = 16 + lr;

  f32x4 acc[2][2];
#pragma unroll
  for (int mt = 0; mt < 2; ++mt)
#pragma unroll
    for (int q = 0; q < 2; ++q)
#pragma unroll
      for (int r = 0; r < 4; ++r) acc[mt][q][r] = 0.f;
#pragma unroll
  for (int kt = 0; kt < 2; ++kt) {
    const short8v a0 = *reinterpret_cast<const short8v*>(
        A + ((row0 * 128 + kt * 64 + lg * 16) ^ sw));
    const short8v a1 = *reinterpret_cast<const short8v*>(
        A + ((row1 * 128 + kt * 64 + lg * 16) ^ sw));
#pragma unroll
    for (int q = 0; q < 2; ++q) {
      const short8v bq = *reinterpret_cast<const short8v*>(
          wp1 + (((size_t)(kt * 8 + 2 * w + q) * 64 + l) << 3));
      acc[0][q] = __builtin_amdgcn_mfma_f32_16x16x32_bf16(a0, bq, acc[0][q], 0, 0, 0);
      acc[1][q] = __builtin_amdgcn_mfma_f32_16x16x32_bf16(a1, bq, acc[1][q], 0, 0, 0);
    }
  }
#pragma unroll
  for (int q = 0; q < 2; ++q) {
    const int col = (2 * w + q) * 16 + lr;
    const float bias = b1[col];
#pragma unroll
    for (int mt = 0; mt < 2; ++mt)
#pragma unroll
      for (int r = 0; r < 4; ++r) {
        const int row = mt * 16 + lg * 4 + r;
        *reinterpret_cast<unsigned short*>(
            Hb + ((row * 256 + col * 2) ^ ((row & 7) << 4))) =
            f2bf(fmaxf(acc[mt][q][r] + bias, 0.f));
      }
  }
  __syncthreads();

  f32x4 acc2[2][2];
#pragma unroll
  for (int mt = 0; mt < 2; ++mt)
#pragma unroll
    for (int q = 0; q < 2; ++q)
#pragma unroll
      for (int r = 0; r < 4; ++r) acc2[mt][q][r] = 0.f;
#pragma unroll
  for (int kt = 0; kt < 4; ++kt) {
    const short8v a0 = *reinterpret_cast<const short8v*>(
        Hb + ((row0 * 256 + kt * 64 + lg * 16) ^ sw));
    const short8v a1 = *reinterpret_cast<const short8v*>(
        Hb + ((row1 * 256 + kt * 64 + lg * 16) ^ sw));
#pragma unroll
    for (int q = 0; q < 2; ++q) {
      const short8v bq = *reinterpret_cast<const short8v*>(
          wp2 + (((size_t)(kt * 8 + 2 * w + q) * 64 + l) << 3));
      acc2[0][q] = __builtin_amdgcn_mfma_f32_16x16x32_bf16(a0, bq, acc2[0][q], 0, 0, 0);
      acc2[1][q] = __builtin_amdgcn_mfma_f32_16x16x32_bf16(a1, bq, acc2[1][q], 0, 0, 0);
    }
  }
#pragma unroll
  for (int q = 0; q < 2; ++q) {
    const int col = (2 * w + q) * 16 + lr;
    const float bias = b2[col];
#pragma unroll
    for (int mt = 0; mt < 2; ++mt)
#pragma unroll
      for (int r = 0; r < 4; ++r) {
        const int row = mt * 16 + lg * 4 + r;
        ef0b[(size_t)(e0 + row) * DF + col] = f2bf(acc2[mt][q][r] + bias);
      }
  }
}

// ---------------------------------------------------------------------------
// Edge MLP via MFMA, bf16 features.  32 edges/block, 4 waves.
// ---------------------------------------------------------------------------
template <bool OUTF>
__global__ __launch_bounds__(256) void k_edge_mlp_mfma(
    const unsigned short* __restrict__ nf0, const unsigned short* __restrict__ nf,
    const unsigned short* __restrict__ ef0, const unsigned short* __restrict__ ef_in,
    void* __restrict__ ef_out, float* __restrict__ agg,
    const int* __restrict__ srcv, const int* __restrict__ dstv,
    const unsigned short* __restrict__ wp1, const float* __restrict__ b1,
    const unsigned short* __restrict__ wp2, const float* __restrict__ b2) {
  __shared__ __align__(16) unsigned char A_lds[32 * 768 * 2];  // 48 KB
  __shared__ int sd[2][32];
  const int t = threadIdx.x;
  const int e0 = blockIdx.x * 32;
  if (t < 32) sd[0][t] = srcv[e0 + t];
  else if (t < 64) sd[1][t - 32] = dstv[e0 + t - 32];
  __syncthreads();

  // gather bf16: 3072 chunks of 16B
#pragma unroll
  for (int j = 0; j < 12; ++j) {
    const int q = j * 256 + t;
    const int c = q & 15;
    const int seg = q >> 4;
    const int i = seg / 6;
    const int p = seg - 6 * i;
    const unsigned short* bp;
    switch (p) {
      case 0: bp = nf0 + (size_t)sd[1][i] * DF; break;
      case 1: bp = nf + (size_t)sd[1][i] * DF; break;
      case 2: bp = nf0 + (size_t)sd[0][i] * DF; break;
      case 3: bp = nf + (size_t)sd[0][i] * DF; break;
      case 4: bp = ef0 + (size_t)(e0 + i) * DF; break;
      default: bp = ef_in + (size_t)(e0 + i) * DF; break;
    }
    const short8v v = *reinterpret_cast<const short8v*>(bp + c * 8);
    *reinterpret_cast<short8v*>(
        A_lds + ((i * 1536 + p * 256 + c * 16) ^ ((i & 7) << 4))) = v;
  }
  __syncthreads();

  const int w = t >> 6, l = t & 63, lr = l & 15, lg = l >> 4;

  f32x4 acc[2][4];
#pragma unroll
  for (int mt = 0; mt < 2; ++mt)
#pragma unroll
    for (int q = 0; q < 4; ++q)
#pragma unroll
      for (int r = 0; r < 4; ++r) acc[mt][q][r] = 0.f;

  const int r0 = lr, r1 = 16 + lr;
  const int off0base = r0 * 1536 + lg * 16;
  const int off1base = r1 * 1536 + lg * 16;
  const int sw0 = (r0 & 7) << 4, sw1 = (r1 & 7) << 4;
#pragma unroll 2
  for (int kt = 0; kt < 24; ++kt) {
    const short8v a0 = *reinterpret_cast<const short8v*>(
        A_lds + ((off0base + kt * 64) ^ sw0));
    const short8v a1 = *reinterpret_cast<const short8v*>(
        A_lds + ((off1base + kt * 64) ^ sw1));
    short8v b[4];
#pragma unroll
    for (int q = 0; q < 4; ++q)
      b[q] = *reinterpret_cast<const short8v*>(
          wp1 + (((size_t)(kt * 16 + 4 * w + q) * 64 + l) << 3));
#pragma unroll
    for (int q = 0; q < 4; ++q) {
      acc[0][q] = __builtin_amdgcn_mfma_f32_16x16x32_bf16(a0, b[q], acc[0][q], 0, 0, 0);
      acc[1][q] = __builtin_amdgcn_mfma_f32_16x16x32_bf16(a1, b[q], acc[1][q], 0, 0, 0);
    }
  }
  __syncthreads();   // everyone done reading A_lds

  // hidden (bias+relu) -> bf16 [32][256] swizzled, reuses A_lds
#pragma unroll
  for (int q = 0; q < 4; ++q) {
    const int col = (4 * w + q) * 16 + lr;
    const float bias = b1[col];
#pragma unroll
    for (int mt = 0; mt < 2; ++mt)
#pragma unroll
      for (int r = 0; r < 4; ++r) {
        const int row = mt * 16 + lg * 4 + r;
        *reinterpret_cast<unsigned short*>(
            A_lds + ((row * 512 + col * 2) ^ ((row & 7) << 4))) =
            f2bf(fmaxf(acc[mt][q][r] + bias, 0.f));
      }
  }
  __syncthreads();

  f32x4 acc2[2][2];
#pragma unroll
  for (int mt = 0; mt < 2; ++mt)
#pragma unroll
    for (int q = 0; q < 2; ++q)
#pragma unroll
      for (int r = 0; r < 4; ++r) acc2[mt][q][r] = 0.f;

  const int hoff0 = r0 * 512 + lg * 16;
  const int hoff1 = r1 * 512 + lg * 16;
#pragma unroll
  for (int kt = 0; kt < 8; ++kt) {
    const short8v a0 = *reinterpret_cast<const short8v*>(
        A_lds + ((hoff0 + kt * 64) ^ sw0));
    const short8v a1 = *reinterpret_cast<const short8v*>(
        A_lds + ((hoff1 + kt * 64) ^ sw1));
    short8v b[2];
#pragma unroll
    for (int q = 0; q < 2; ++q)
      b[q] = *reinterpret_cast<const short8v*>(
          wp2 + (((size_t)(kt * 8 + 2 * w + q) * 64 + l) << 3));
#pragma unroll
    for (int q = 0; q < 2; ++q) {
      acc2[0][q] = __builtin_amdgcn_mfma_f32_16x16x32_bf16(a0, b[q], acc2[0][q], 0, 0, 0);
      acc2[1][q] = __builtin_amdgcn_mfma_f32_16x16x32_bf16(a1, b[q], acc2[1][q], 0, 0, 0);
    }
  }

#pragma unroll
  for (int q = 0; q < 2; ++q) {
    const int n = (2 * w + q) * 16 + lr;
    const float bias = b2[n];
#pragma unroll
    for (int mt = 0; mt < 2; ++mt)
#pragma unroll
      for (int r = 0; r < 4; ++r) {
        const int m = mt * 16 + lg * 4 + r;
        const float v = acc2[mt][q][r] + bias;
        if (OUTF)
          ((float*)ef_out)[(size_t)(e0 + m) * DF + n] = v;
        else
          ((unsigned short*)ef_out)[(size_t)(e0 + m) * DF + n] = f2bf(v);
        atomicAdd(&agg[(size_t)sd[1][m] * DF + n], v);
      }
  }
}

// ---------------------------------------------------------------------------
// Node update MFMA: [nf0|nf|agg] (384) @ w + b, 32 nodes/block.
// ---------------------------------------------------------------------------
template <bool OUTF>
__global__ __launch_bounds__(256) void k_node_update_mfma(
    const unsigned short* __restrict__ nf0, const unsigned short* __restrict__ nfb,
    const float* __restrict__ agg, void* __restrict__ outp,
    const unsigned short* __restrict__ wp, const float* __restrict__ b) {
  __shared__ __align__(16) unsigned char A[32 * 768];   // 32 x 384 bf16
  const int t = threadIdx.x;
  const int n0 = blockIdx.x * 32;
#pragma unroll
  for (int j = 0; j < 6; ++j) {
    const int q = j * 256 + t;
    const int i = q / 48;
    const int cc = q - i * 48;
    const int p = cc >> 4, c = cc & 15;
    const int row = n0 + i;
    short8v o;
    if (p == 0)
      o = *reinterpret_cast<const short8v*>(nf0 + (size_t)row * DF + c * 8);
    else if (p == 1)
      o = *reinterpret_cast<const short8v*>(nfb + (size_t)row * DF + c * 8);
    else {
      const float* ar = agg + (size_t)row * DF + c * 8;
      o = pack8(*reinterpret_cast<const float4*>(ar),
                *reinterpret_cast<const float4*>(ar + 4));
    }
    *reinterpret_cast<short8v*>(
        A + ((i * 768 + p * 256 + c * 16) ^ ((i & 7) << 4))) = o;
  }
  __syncthreads();

  const int w = t >> 6, l = t & 63, lr = l & 15, lg = l >> 4;
  const int sw = (lr & 7) << 4;
  const int row0 = lr, row1 = 16 + lr;

  f32x4 acc[2][2];
#pragma unroll
  for (int mt = 0; mt < 2; ++mt)
#pragma unroll
    for (int q = 0; q < 2; ++q)
#pragma unroll
      for (int r = 0; r < 4; ++r) acc[mt][q][r] = 0.f;
#pragma unroll
  for (int kt = 0; kt < 12; ++kt) {
    const short8v a0 = *reinterpret_cast<const short8v*>(
        A + ((row0 * 768 + kt * 64 + lg * 16) ^ sw));
    const short8v a1 = *reinterpret_cast<const short8v*>(
        A + ((row1 * 768 + kt * 64 + lg * 16) ^ sw));
#pragma unroll
    for (int q = 0; q < 2; ++q) {
      const short8v bq = *reinterpret_cast<const short8v*>(
          wp + (((size_t)(kt * 8 + 2 * w + q) * 64 + l) << 3));
      acc[0][q] = __builtin_amdgcn_mfma_f32_16x16x32_bf16(a0, bq, acc[0][q], 0, 0, 0);
      acc[1][q] = __builtin_amdgcn_mfma_f32_16x16x32_bf16(a1, bq, acc[1][q], 0, 0, 0);
    }
  }
#pragma unroll
  for (int q = 0; q < 2; ++q) {
    const int col = (2 * w + q) * 16 + lr;
    const float bias = b[col];
#pragma unroll
    for (int mt = 0; mt < 2; ++mt)
#pragma unroll
      for (int r = 0; r < 4; ++r) {
        const int row = mt * 16 + lg * 4 + r;
        const float v = acc[mt][q][r] + bias;
        if (OUTF)
          ((float*)outp)[(size_t)(n0 + row) * DF + col] = v;
        else
          ((unsigned short*)outp)[(size_t)(n0 + row) * DF + col] = f2bf(v);
      }
  }
}

// ---------------------------------------------------------------------------
// Scalar classifier: relu(f @ w1 + b1) . w2 + b2, 32 rows/block.
// Layer1 MFMA, layer2 VALU reduce.
// ---------------------------------------------------------------------------
template <bool INBF>
__global__ __launch_bounds__(256) void k_cls_scalar_mfma(
    const void* __restrict__ feat, const unsigned short* __restrict__ wp,
    const float* __restrict__ b1, const float* __restrict__ w2,
    const float* __restrict__ b2, float* __restrict__ out) {
  __shared__ __align__(16) unsigned char A[32 * 256];  // 32 x 128 bf16
  __shared__ float hid[32][136];
  __shared__ float w2s[DF];
  __shared__ float part[32][8];
  const int t = threadIdx.x;
  const int r0 = blockIdx.x * 32;
  if (t < DF) w2s[t] = w2[t];
#pragma unroll
  for (int j = 0; j < 2; ++j) {
    const int q = j * 256 + t;
    const int i = q >> 4, c = q & 15;
    short8v o;
    if (INBF) {
      o = *reinterpret_cast<const short8v*>(
          (const unsigned short*)feat + (size_t)(r0 + i) * DF + c * 8);
    } else {
      const float* fr = (const float*)feat + (size_t)(r0 + i) * DF + c * 8;
      o = pack8(*reinterpret_cast<const float4*>(fr),
                *reinterpret_cast<const float4*>(fr + 4));
    }
    *reinterpret_cast<short8v*>(A + ((i * 256 + c * 16) ^ ((i & 7) << 4))) = o;
  }
  __syncthreads();

  const int w = t >> 6, l = t & 63, lr = l & 15, lg = l >> 4;
  const int sw = (lr & 7) << 4;
  const int row0 = lr, row1 = 16 + lr;
  f32x4 acc[2][2];
#pragma unroll
  for (int mt = 0; mt < 2; ++mt)
#pragma unroll
    for (int q = 0; q < 2; ++q)
#pragma unroll
      for (int r = 0; r < 4; ++r) acc[mt][q][r] = 0.f;
#pragma unroll
  for (int kt = 0; kt < 4; ++kt) {
    const short8v a0 = *reinterpret_cast<const short8v*>(
        A + ((row0 * 256 + kt * 64 + lg * 16) ^ sw));
    const short8v a1 = *reinterpret_cast<const short8v*>(
        A + ((row1 * 256 + kt * 64 + lg * 16) ^ sw));
#pragma unroll
    for (int q = 0; q < 2; ++q) {
      const short8v bq = *reinterpret_cast<const short8v*>(
          wp + (((size_t)(kt * 8 + 2 * w + q) * 64 + l) << 3));
      acc[0][q] = __builtin_amdgcn_mfma_f32_16x16x32_bf16(a0, bq, acc[0][q], 0, 0, 0);
      acc[1][q] = __builtin_amdgcn_mfma_f32_16x16x32_bf16(a1, bq, acc[1][q], 0, 0, 0);
    }
  }
#pragma unroll
  for (int q = 0; q < 2; ++q) {
    const int col = (2 * w + q) * 16 + lr;
    const float bias = b1[col];
#pragma unroll
    for (int mt = 0; mt < 2; ++mt)
#pragma unroll
      for (int r = 0; r < 4; ++r) {
        const int row = mt * 16 + lg * 4 + r;
        hid[row][col] = fmaxf(acc[mt][q][r] + bias, 0.f);
      }
  }
  __syncthreads();
  {
    const int r = t >> 3, kc = t & 7;
    float s = 0.f;
#pragma unroll
    for (int u = 0; u < 16; ++u) s = fmaf(hid[r][kc * 16 + u], w2s[kc * 16 + u], s);
    part[r][kc] = s;
  }
  __syncthreads();
  if (t < 32) {
    float s = b2[0];
#pragma unroll
    for (int k = 0; k < 8; ++k) s += part[t][k];
    out[r0 + t] = s;
  }
}

// ---------------------------------------------------------------------------
// Class classifier: relu(f @ w1 + b1) @ w2[128,17] + b2, fp32 input.
// ---------------------------------------------------------------------------
__global__ __launch_bounds__(256) void k_cls_class_mfma(
    const float* __restrict__ feat, const unsigned short* __restrict__ wp,
    const float* __restrict__ b1, const float* __restrict__ w2,
    const float* __restrict__ b2, float* __restrict__ out) {
  __shared__ __align__(16) unsigned char A[32 * 256];
  __shared__ float hid[32][136];
  __shared__ float w2s[DF * TT];
  const int t = threadIdx.x;
  const int r0 = blockIdx.x * 32;
  for (int j = t; j < DF * TT; j += 256) w2s[j] = w2[j];
#pragma unroll
  for (int j = 0; j < 2; ++j) {
    const int q = j * 256 + t;
    const int i = q >> 4, c = q & 15;
    const float* fr = feat + (size_t)(r0 + i) * DF + c * 8;
    const short8v o = pack8(*reinterpret_cast<const float4*>(fr),
                            *reinterpret_cast<const float4*>(fr + 4));
    *reinterpret_cast<short8v*>(A + ((i * 256 + c * 16) ^ ((i & 7) << 4))) = o;
  }
  __syncthreads();

  const int w = t >> 6, l = t & 63, lr = l & 15, lg = l >> 4;
  const int sw = (lr & 7) << 4;
  const int row0 = lr, row1 = 16 + lr;
  f32x4 acc[2][2];
#pragma unroll
  for (int mt = 0; mt < 2; ++mt)
#pragma unroll
    for (int q = 0; q < 2; ++q)
#pragma unroll
      for (int r = 0; r < 4; ++r) acc[mt][q][r] = 0.f;
#pragma unroll
  for (int kt = 0; kt < 4; ++kt) {
    const short8v a0 = *reinterpret_cast<const short8v*>(
        A + ((row0 * 256 + kt * 64 + lg * 16) ^ sw));
    const short8v a1 = *reinterpret_cast<const short8v*>(
        A + ((row1 * 256 + kt * 64 + lg * 16) ^ sw));
#pragma unroll
    for (int q = 0; q < 2; ++q) {
      const short8v bq = *reinterpret_cast<const short8v*>(
          wp + (((size_t)(kt * 8 + 2 * w + q) * 64 + l) << 3));
      acc[0][q] = __builtin_amdgcn_mfma_f32_16x16x32_bf16(a0, bq, acc[0][q], 0, 0, 0);
      acc[1][q] = __builtin_amdgcn_mfma_f32_16x16x32_bf16(a1, bq, acc[1][q], 0, 0, 0);
    }
  }
#pragma unroll
  for (int q = 0; q < 2; ++q) {
    const int col = (2 * w + q) * 16 + lr;
    const float bias = b1[col];
#pragma unroll
    for (int mt = 0; mt < 2; ++mt)
#pragma unroll
      for (int r = 0; r < 4; ++r) {
        const int row = mt * 16 + lg * 4 + r;
        hid[row][col] = fmaxf(acc[mt][q][r] + bias, 0.f);
      }
  }
  __syncthreads();
  for (int o = t; o < 32 * TT; o += 256) {
    const int r = o / TT, c = o - TT * r;
    float s = b2[c];
    for (int k = 0; k < DF; ++k) s = fmaf(hid[r][k], w2s[k * TT + c], s);
    out[(size_t)(r0 + r) * TT + c] = s;
  }
}

// ---------------------------------------------------------------------------
extern "C" void kernel_launch(void* const* d_in, const int* in_sizes, int n_in,
                              void* d_out, int out_size, void* d_ws,
                              size_t ws_size, hipStream_t stream) {
  (void)in_sizes; (void)n_in; (void)out_size; (void)ws_size;
  const float* x         = (const float*)d_in[0];
  const float* edge_attr = (const float*)d_in[1];
  const int*   edge_idx  = (const int*)d_in[2];
  const int*   node_ty   = (const int*)d_in[3];
  const float* ne_w1 = (const float*)d_in[4];
  const float* ne_b1 = (const float*)d_in[5];
  const float* ne_w2 = (const float*)d_in[6];
  const float* ne_b2 = (const float*)d_in[7];
  const float* ee_w1 = (const float*)d_in[8];
  const float* ee_b1 = (const float*)d_in[9];
  const float* ee_w2 = (const float*)d_in[10];
  const float* ee_b2 = (const float*)d_in[11];
  const float* me_w1 = (const float*)d_in[12];
  const float* me_b1 = (const float*)d_in[13];
  const float* me_w2 = (const float*)d_in[14];
  const float* me_b2 = (const float*)d_in[15];
  const float* mn_w1 = (const float*)d_in[16];
  const float* mn_b1 = (const float*)d_in[17];
  const float* ec_w1 = (const float*)d_in[18];
  const float* ec_b1 = (const float*)d_in[19];
  const float* ec_w2 = (const float*)d_in[20];
  const float* ec_b2 = (const float*)d_in[21];
  const float* nc_w1 = (const float*)d_in[22];
  const float* nc_b1 = (const float*)d_in[23];
  const float* nc_w2 = (const float*)d_in[24];
  const float* nc_b2 = (const float*)d_in[25];
  const float* cc_w1 = (const float*)d_in[26];
  const float* cc_b1 = (const float*)d_in[27];
  const float* cc_w2 = (const float*)d_in[28];
  const float* cc_b2 = (const float*)d_in[29];

  const int* srcv = edge_idx;
  const int* dstv = edge_idx + N_EDGES;

  // ---- workspace layout ----
  float* agg = (float*)d_ws;                               // 2.56M f
  unsigned short* nf0b = (unsigned short*)(agg + (size_t)N_NODES * DF);
  unsigned short* nf1b = nf0b + (size_t)N_NODES * DF;
  unsigned short* ef0b = nf1b + (size_t)N_NODES * DF;
  unsigned short* ef1b = ef0b + (size_t)N_EDGES * DF;
  unsigned short* wme1 = ef1b + (size_t)N_EDGES * DF;      // 768x256
  unsigned short* wme2 = wme1 + 768 * 256;                 // 256x128
  unsigned short* wmn  = wme2 + 256 * 128;                 // 384x128
  unsigned short* wne1 = wmn + 384 * 128;                  // 17 x 256x128
  unsigned short* wne2 = wne1 + (size_t)TT * 256 * 128;    // 17 x 128x128
  unsigned short* wee1 = wne2 + (size_t)TT * 128 * 128;    // 64x128
  unsigned short* wee2 = wee1 + 64 * 128;                  // 128x128
  unsigned short* wec  = wee2 + 128 * 128;
  unsigned short* wnc  = wec + 128 * 128;
  unsigned short* wcc  = wnc + 128 * 128;
  int* cnt    = (int*)(wcc + 128 * 128);
  int* poff   = cnt + 32;
  int* woff   = poff + 32;
  int* bucket = woff + 32;                                 // 20544 ints

  // ---- output layout ----
  float* out_pe = (float*)d_out;
  float* out_pn = out_pe + N_EDGES;
  float* out_pc = out_pn + N_NODES;
  float* out_nf = out_pc + (size_t)N_NODES * TT;
  float* out_ef = out_nf + (size_t)N_NODES * DF;

  // ---- weight packing ----
  k_pack_w<<<96, 256, 0, stream>>>(me_w1, wme1, 768, 256, 1);
  k_pack_w<<<16, 256, 0, stream>>>(me_w2, wme2, 256, 128, 1);
  k_pack_w<<<24, 256, 0, stream>>>(mn_w1, wmn, 384, 128, 1);
  k_pack_w<<<272, 256, 0, stream>>>(ne_w1, wne1, 256, 128, TT);
  k_pack_w<<<136, 256, 0, stream>>>(ne_w2, wne2, 128, 128, TT);
  k_pack_w<<<4, 256, 0, stream>>>(ee_w1, wee1, 64, 128, 1);
  k_pack_w<<<8, 256, 0, stream>>>(ee_w2, wee2, 128, 128, 1);
  k_pack_w<<<8, 256, 0, stream>>>(ec_w1, wec, 128, 128, 1);
  k_pack_w<<<8, 256, 0, stream>>>(nc_w1, wnc, 128, 128, 1);
  k_pack_w<<<8, 256, 0, stream>>>(cc_w1, wcc, 128, 128, 1);

  // ---- type bucketing ----
  hipMemsetAsync(cnt, 0, 32 * sizeof(int), stream);
  hipMemsetAsync(bucket, 0xFF, NE_PAD_SLOTS * sizeof(int), stream);
  k_count<<<(N_NODES + 255) / 256, 256, 0, stream>>>(node_ty, cnt);
  k_prefix<<<1, 64, 0, stream>>>(cnt, poff, woff);
  k_scatter<<<(N_NODES + 255) / 256, 256, 0, stream>>>(node_ty, woff, bucket);

  // ---- embeddings ----
  k_node_embed_mfma<<<NE_PAD_SLOTS / 32, 256, 0, stream>>>(
      x, bucket, node_ty, wne1, ne_b1, wne2, ne_b2, nf0b);
  k_edge_embed_mfma<<<N_EDGES / 32, 256, 0, stream>>>(edge_attr, wee1, ee_b1,
                                                      wee2, ee_b2, ef0b);

  // ---- mp step 1 ----
  hipMemsetAsync(agg, 0, (size_t)N_NODES * DF * sizeof(float), stream);
  k_edge_mlp_mfma<false><<<N_EDGES / 32, 256, 0, stream>>>(
      nf0b, nf0b, ef0b, ef0b, (void*)ef1b, agg, srcv, dstv, wme1, me_b1, wme2, me_b2);
  k_node_update_mfma<false><<<N_NODES / 32, 256, 0, stream>>>(
      nf0b, nf0b, agg, (void*)nf1b, wmn, mn_b1);
  // ---- mp step 2 ----
  hipMemsetAsync(agg, 0, (size_t)N_NODES * DF * sizeof(float), stream);
  k_edge_mlp_mfma<false><<<N_EDGES / 32, 256, 0, stream>>>(
      nf0b, nf1b, ef0b, ef1b, (void*)ef1b, agg, srcv, dstv, wme1, me_b1, wme2, me_b2);
  k_node_update_mfma<false><<<N_NODES / 32, 256, 0, stream>>>(
      nf0b, nf1b, agg, (void*)nf1b, wmn, mn_b1);
  // pred_edge from ef after 2 steps
  k_cls_scalar_mfma<true><<<N_EDGES / 32, 256, 0, stream>>>(
      (const void*)ef1b, wec, ec_b1, ec_w2, ec_b2, out_pe);
  // ---- mp step 3 ----
  hipMemsetAsync(agg, 0, (size_t)N_NODES * DF * sizeof(float), stream);
  k_edge_mlp_mfma<true><<<N_EDGES / 32, 256, 0, stream>>>(
      nf0b, nf1b, ef0b, ef1b, (void*)out_ef, agg, srcv, dstv, wme1, me_b1, wme2, me_b2);
  k_node_update_mfma<true><<<N_NODES / 32, 256, 0, stream>>>(
      nf0b, nf1b, agg, (void*)out_nf, wmn, mn_b1);

  // ---- heads ----
  k_cls_scalar_mfma<false><<<N_NODES / 32, 256, 0, stream>>>(
      (const void*)out_nf, wnc, nc_b1, nc_w2, nc_b2, out_pn);
  k_cls_class_mfma<<<N_NODES / 32, 256, 0, stream>>>(out_nf, wcc, cc_b1, cc_w2,
                                                     cc_b2, out_pc);
}